// Round 3
// baseline (834.106 us; speedup 1.0000x reference)
//
#include <hip/hip_runtime.h>

namespace {

constexpr int T = 1024;
constexpr int B = 1024;
constexpr int L = 10;
constexpr int H = 10;
constexpr int NTHREADS = 128;      // 2 waves: wave0 = layers 0-5 (b-pair), wave1 = layers 6-9
constexpr int NB = 2;              // batch elements per block (dual-chain ILP)
constexpr int U = 4;               // timesteps per interval
constexpr int NWIN = T / U;        // 256 windows
constexpr int NINT = NWIN + L - 1; // 265 intervals
constexpr int BH = B * H;
constexpr int ROWF = 20;           // splat-pair row: (v0,v0,v1,v1,...,v9,v9)

using v2f = __attribute__((ext_vector_type(2))) float;
using v4f = __attribute__((ext_vector_type(4))) float;

__device__ __forceinline__ v2f v2fma(v2f a, v2f b, v2f c) {
    return __builtin_elementwise_fma(a, b, c);   // v_pk_fma_f32
}
__device__ __forceinline__ void pin2(v2f& v) { asm volatile("" : "+v"(v)); }
__device__ __forceinline__ float rcp_f(float x) { return __builtin_amdgcn_rcpf(x); }
__device__ __forceinline__ v2f lo2(v4f q) { return __builtin_shufflevector(q, q, 0, 1); }
__device__ __forceinline__ v2f hi2(v4f q) { return __builtin_shufflevector(q, q, 2, 3); }

__global__
__attribute__((amdgpu_flat_work_group_size(NTHREADS, NTHREADS)))
__attribute__((amdgpu_waves_per_eu(1)))   // 1 wave/SIMD by grid; allow full VGPR budget
void lstm_pipeline(const float* __restrict__ x,    // [T,B,H]
                   const float* __restrict__ hp,   // [L,B,H]
                   const float* __restrict__ cp,   // [L,B,H]
                   const float* __restrict__ Wih,  // [L,4H,H]
                   const float* __restrict__ Whh,  // [L,4H,H]
                   const float* __restrict__ bih,  // [L,4H]
                   const float* __restrict__ bhh,  // [L,4H]
                   float* __restrict__ out,        // [T,B,H]
                   float* __restrict__ hn,         // [L,B,H]
                   float* __restrict__ cn)         // [L,B,H]
{
    // [b][parity][u][layer][splat row]; layer stride 20 floats -> distinct banks
    // per layer group; all j-lanes of a layer read the same 16B (broadcast).
    __shared__ __align__(16) float buf[NB][2][U][L + 1][ROWF];   // 14080 B

    const int tid = threadIdx.x;
    const int wv = tid >> 6;
    const int ln = tid & 63;
    // (l,j) mapping, proven in prior rounds. Dup lanes repeat valid items of
    // the same wave -> identical values/addresses, benign.
    int lidx;
    if (wv == 0) lidx = (ln < 60) ? ln : (ln - 10);              // dup l=5,j=0..3
    else         lidx = (ln < 40) ? (60 + ln) : (90 + (ln - 40) % 10);  // dup l=9
    const int l = lidx / 10;
    const int j = lidx % 10;
    const int bbase = blockIdx.x * NB;

    // x stagers: wave0 lanes 0-9 stage b0; wave1 dup-lanes 40-49 stage b1.
    const bool is_st = (wv == 0) ? (ln < 10) : (ln >= 40 && ln < 50);
    const int stb = wv;                             // which b this lane stages
    const int stj = (wv == 0) ? ln : (ln - 40);
    const int stboff = (bbase + stb) * H + stj;

    // ---- weights global -> registers, gate-pair packed ----
    // chainA component0 = gate i (rows 0..9), comp1 = gate f (rows 10..19)
    // chainB component0 = gate g (rows 20..29), comp1 = gate o (rows 30..39)
    v2f wiA[10], wiB[10], whA[10], whB[10], bA, bB;
    {
        const float* WiL = Wih + (size_t)l * 4 * H * H;
        const float* WhL = Whh + (size_t)l * 4 * H * H;
        #pragma unroll
        for (int k = 0; k < 10; ++k) {
            wiA[k][0] = WiL[(0 * H + j) * H + k]; wiA[k][1] = WiL[(1 * H + j) * H + k];
            wiB[k][0] = WiL[(2 * H + j) * H + k]; wiB[k][1] = WiL[(3 * H + j) * H + k];
            whA[k][0] = WhL[(0 * H + j) * H + k]; whA[k][1] = WhL[(1 * H + j) * H + k];
            whB[k][0] = WhL[(2 * H + j) * H + k]; whB[k][1] = WhL[(3 * H + j) * H + k];
        }
        const int bo = l * 4 * H;
        bA[0] = bih[bo + j] + bhh[bo + j];
        bA[1] = bih[bo + H + j] + bhh[bo + H + j];
        bB[0] = bih[bo + 2 * H + j] + bhh[bo + 2 * H + j];
        bB[1] = bih[bo + 3 * H + j] + bhh[bo + 3 * H + j];
    }
    #pragma unroll
    for (int k = 0; k < 10; ++k) { pin2(wiA[k]); pin2(wiB[k]); pin2(whA[k]); pin2(whB[k]); }
    pin2(bA); pin2(bB);

    // ---- state for both batch elements; seed h(-1) rows at both parities ----
    float hs[NB], cs[NB];
    #pragma unroll
    for (int bb = 0; bb < NB; ++bb) {
        hs[bb] = hp[((size_t)l * B + bbase + bb) * H + j];
        cs[bb] = cp[((size_t)l * B + bbase + bb) * H + j];
        v2f hh; hh[0] = hs[bb]; hh[1] = hs[bb];
        *(v2f*)&buf[bb][0][U - 1][l + 1][2 * j] = hh;
        *(v2f*)&buf[bb][1][U - 1][l + 1][2 * j] = hh;
    }

    float xcur[U], xnext[U];
    if (is_st) {
        #pragma unroll
        for (int u = 0; u < U; ++u) {
            float xv = x[(size_t)u * BH + stboff];
            v2f xx; xx[0] = xv; xx[1] = xv;
            *(v2f*)&buf[stb][1][u][0][2 * stj] = xx;       // window 0 (rp=1 first)
        }
        #pragma unroll
        for (int u = 0; u < U; ++u) xcur[u] = x[(size_t)(U + u) * BH + stboff];
    }
    __syncthreads();

    auto interval = [&](int k, int wp, int rp) {
        // Prefetch x window k+2 (global latency amortized across interval).
        if (is_st && (k + 2) < NWIN) {
            #pragma unroll
            for (int u = 0; u < U; ++u)
                xnext[u] = x[(size_t)((k + 2) * U + u) * BH + stboff];
        }
        const unsigned w = (unsigned)(k - l);
        if (w < (unsigned)NWIN) {
            // ---- phase 1: x-projections for both b, all 4 timesteps ----
            v2f aA[NB][U], aB[NB][U];
            #pragma unroll
            for (int bb = 0; bb < NB; ++bb) {
                #pragma unroll
                for (int u = 0; u < U; ++u) {
                    const float* xr = &buf[bb][rp][u][l][0];
                    v4f q0 = *(const v4f*)(xr + 0);
                    v4f q1 = *(const v4f*)(xr + 4);
                    v4f q2 = *(const v4f*)(xr + 8);
                    v4f q3 = *(const v4f*)(xr + 12);
                    v4f q4 = *(const v4f*)(xr + 16);
                    v2f a  = v2fma(wiA[0], lo2(q0), bA);
                    v2f bv = v2fma(wiB[0], lo2(q0), bB);
                    a = v2fma(wiA[1], hi2(q0), a);  bv = v2fma(wiB[1], hi2(q0), bv);
                    a = v2fma(wiA[2], lo2(q1), a);  bv = v2fma(wiB[2], lo2(q1), bv);
                    a = v2fma(wiA[3], hi2(q1), a);  bv = v2fma(wiB[3], hi2(q1), bv);
                    a = v2fma(wiA[4], lo2(q2), a);  bv = v2fma(wiB[4], lo2(q2), bv);
                    a = v2fma(wiA[5], hi2(q2), a);  bv = v2fma(wiB[5], hi2(q2), bv);
                    a = v2fma(wiA[6], lo2(q3), a);  bv = v2fma(wiB[6], lo2(q3), bv);
                    a = v2fma(wiA[7], hi2(q3), a);  bv = v2fma(wiB[7], hi2(q3), bv);
                    a = v2fma(wiA[8], lo2(q4), a);  bv = v2fma(wiB[8], lo2(q4), bv);
                    a = v2fma(wiA[9], hi2(q4), a);  bv = v2fma(wiB[9], hi2(q4), bv);
                    aA[bb][u] = a; aB[bb][u] = bv;
                }
            }
            // ---- phase 2: serial recurrence, both b interleaved ----
            float hv[NB][U];
            #pragma unroll
            for (int u = 0; u < U; ++u) {
                v2f pA[NB], pB[NB];
                #pragma unroll
                for (int bb = 0; bb < NB; ++bb) {
                    // own-layer h row lives at [l+1] (also consumed by layer l+1)
                    const float* hr = (u == 0) ? &buf[bb][rp][U - 1][l + 1][0]
                                               : &buf[bb][wp][u - 1][l + 1][0];
                    v4f q0 = *(const v4f*)(hr + 0);
                    v4f q1 = *(const v4f*)(hr + 4);
                    v4f q2 = *(const v4f*)(hr + 8);
                    v4f q3 = *(const v4f*)(hr + 12);
                    v4f q4 = *(const v4f*)(hr + 16);
                    v2f a  = v2fma(whA[0], lo2(q0), aA[bb][u]);
                    v2f bv = v2fma(whB[0], lo2(q0), aB[bb][u]);
                    a = v2fma(whA[1], hi2(q0), a);  bv = v2fma(whB[1], hi2(q0), bv);
                    a = v2fma(whA[2], lo2(q1), a);  bv = v2fma(whB[2], lo2(q1), bv);
                    a = v2fma(whA[3], hi2(q1), a);  bv = v2fma(whB[3], hi2(q1), bv);
                    a = v2fma(whA[4], lo2(q2), a);  bv = v2fma(whB[4], lo2(q2), bv);
                    a = v2fma(whA[5], hi2(q2), a);  bv = v2fma(whB[5], hi2(q2), bv);
                    a = v2fma(whA[6], lo2(q3), a);  bv = v2fma(whB[6], lo2(q3), bv);
                    a = v2fma(whA[7], hi2(q3), a);  bv = v2fma(whB[7], hi2(q3), bv);
                    a = v2fma(whA[8], lo2(q4), a);  bv = v2fma(whB[8], lo2(q4), bv);
                    a = v2fma(whA[9], hi2(q4), a);  bv = v2fma(whB[9], hi2(q4), bv);
                    pA[bb] = a; pB[bb] = bv;
                }
                // activations: same formulas as passing kernel, staged so the
                // two b-chains' trans ops interleave
                float ei[NB], ef[NB], eg[NB], eo[NB];
                #pragma unroll
                for (int bb = 0; bb < NB; ++bb) {
                    ei[bb] = __expf(-pA[bb][0]);
                    ef[bb] = __expf(-pA[bb][1]);
                    eg[bb] = __expf(2.0f * pB[bb][0]);
                    eo[bb] = __expf(-pB[bb][1]);
                }
                float ig[NB], fg[NB], gr[NB], og[NB];
                #pragma unroll
                for (int bb = 0; bb < NB; ++bb) {
                    ig[bb] = rcp_f(1.0f + ei[bb]);
                    fg[bb] = rcp_f(1.0f + ef[bb]);
                    gr[bb] = rcp_f(1.0f + eg[bb]);
                    og[bb] = rcp_f(1.0f + eo[bb]);
                }
                float et[NB];
                #pragma unroll
                for (int bb = 0; bb < NB; ++bb) {
                    const float gg = 1.0f - 2.0f * gr[bb];       // tanh(pre_g)
                    cs[bb] = fmaf(fg[bb], cs[bb], ig[bb] * gg);
                    et[bb] = __expf(2.0f * cs[bb]);
                }
                #pragma unroll
                for (int bb = 0; bb < NB; ++bb) {
                    const float th = 1.0f - 2.0f * rcp_f(1.0f + et[bb]);  // tanh(c)
                    const float h = og[bb] * th;
                    hs[bb] = h;
                    v2f hh; hh[0] = h; hh[1] = h;
                    *(v2f*)&buf[bb][wp][u][l + 1][2 * j] = hh;   // l=9 -> pad row 10
                    hv[bb][u] = h;
                }
            }
            if (l == L - 1) {                 // batched out-stores (dups benign)
                const int t0 = (int)w * U;
                #pragma unroll
                for (int bb = 0; bb < NB; ++bb)
                    #pragma unroll
                    for (int u = 0; u < U; ++u)
                        out[(size_t)(t0 + u) * BH + (bbase + bb) * H + j] = hv[bb][u];
            }
        }
        // Stage x window k+1 for the next interval.
        if (is_st && (k + 1) < NWIN) {
            #pragma unroll
            for (int u = 0; u < U; ++u) {
                v2f xx; xx[0] = xcur[u]; xx[1] = xcur[u];
                *(v2f*)&buf[stb][wp][u][0][2 * stj] = xx;
            }
            #pragma unroll
            for (int u = 0; u < U; ++u) xcur[u] = xnext[u];
        }
        __syncthreads();
    };

    for (int kk = 0; kk < NINT + 1; kk += 2) {   // literal parities
        interval(kk, 0, 1);
        interval(kk + 1, 1, 0);
    }

    #pragma unroll
    for (int bb = 0; bb < NB; ++bb) {
        hn[((size_t)l * B + bbase + bb) * H + j] = hs[bb];   // dups store same values
        cn[((size_t)l * B + bbase + bb) * H + j] = cs[bb];
    }
}

} // namespace

extern "C" void kernel_launch(void* const* d_in, const int* in_sizes, int n_in,
                              void* d_out, int out_size, void* d_ws, size_t ws_size,
                              hipStream_t stream) {
    (void)in_sizes; (void)n_in; (void)d_ws; (void)ws_size; (void)out_size;
    const float* x   = (const float*)d_in[0];
    const float* hp  = (const float*)d_in[1];
    const float* cp  = (const float*)d_in[2];
    const float* Wih = (const float*)d_in[3];
    const float* Whh = (const float*)d_in[4];
    const float* bih = (const float*)d_in[5];
    const float* bhh = (const float*)d_in[6];

    float* out = (float*)d_out;
    float* hn  = out + (size_t)T * B * H;
    float* cn  = hn + (size_t)L * B * H;

    lstm_pipeline<<<dim3(B / NB), dim3(NTHREADS), 0, stream>>>(
        x, hp, cp, Wih, Whh, bih, bhh, out, hn, cn);
}

// Round 4
// 537.521 us; speedup vs baseline: 1.5518x; 1.5518x over previous
//
#include <hip/hip_runtime.h>

namespace {

constexpr int T = 1024;
constexpr int B = 1024;
constexpr int L = 10;
constexpr int H = 10;
constexpr int NTHREADS = 128;      // 2 waves: wave0 = layers 0-5, wave1 = layers 6-9
constexpr int U = 4;               // timesteps per interval
constexpr int NWIN = T / U;        // 256 windows
constexpr int NINT = NWIN + L - 1; // 265 intervals
constexpr int BH = B * H;
constexpr int ROWF = 20;           // splat-pair row: (v0,v0,v1,v1,...,v9,v9)
constexpr int P = 4;               // intervals per epoch (one barrier per epoch)
constexpr int DELAY = P - 1;       // wave1 lags wave0 by 3 intervals
constexpr int D = 2 * P;           // slot depth 8 (RAW: k-1 vs k+3 cross-epoch;
                                   //  WAR: slot reuse at k+7, >= 1 epoch later)
constexpr int NROUNDS = ((NINT + DELAY + P - 1) / P) * P;  // 268

using v2f = __attribute__((ext_vector_type(2))) float;
using v4f = __attribute__((ext_vector_type(4))) float;

__device__ __forceinline__ v2f v2fma(v2f a, v2f b, v2f c) {
    return __builtin_elementwise_fma(a, b, c);   // v_pk_fma_f32
}
__device__ __forceinline__ void pin2(v2f& v) { asm volatile("" : "+v"(v)); }
__device__ __forceinline__ float rcp_f(float x) { return __builtin_amdgcn_rcpf(x); }
__device__ __forceinline__ v2f lo2(v4f q) { return __builtin_shufflevector(q, q, 0, 1); }
__device__ __forceinline__ v2f hi2(v4f q) { return __builtin_shufflevector(q, q, 2, 3); }

__global__
__attribute__((amdgpu_flat_work_group_size(NTHREADS, NTHREADS)))
__attribute__((amdgpu_waves_per_eu(2)))   // cap VGPR at 256; 2 waves/SIMD resident
void lstm_pipeline(const float* __restrict__ x,    // [T,B,H]
                   const float* __restrict__ hp,   // [L,B,H]
                   const float* __restrict__ cp,   // [L,B,H]
                   const float* __restrict__ Wih,  // [L,4H,H]
                   const float* __restrict__ Whh,  // [L,4H,H]
                   const float* __restrict__ bih,  // [L,4H]
                   const float* __restrict__ bhh,  // [L,4H]
                   float* __restrict__ out,        // [T,B,H]
                   float* __restrict__ hn,         // [L,B,H]
                   float* __restrict__ cn)         // [L,B,H]
{
    // [slot][u][row][splat row]. Row r = input of layer r (r=0: x; r=l+1:
    // layer-l output = layer-l own h). Slot(k) holds data produced at
    // interval k, consumed at interval k+1 (slot_r = slot(k-1)).
    __shared__ __align__(16) float buf[D][U][L + 1][ROWF];   // 28160 B

    const int tid = threadIdx.x;
    const int wv = tid >> 6;
    const int ln = tid & 63;
    // (l,j) mapping, proven in prior rounds. Dup lanes repeat valid items of
    // the same wave -> identical values/addresses, benign.
    int lidx;
    if (wv == 0) lidx = (ln < 60) ? ln : (ln - 10);              // dup l=5,j=0..3
    else         lidx = (ln < 40) ? (60 + ln) : (90 + (ln - 40) % 10);  // dup l=9
    const int l = lidx / 10;
    const int j = lidx % 10;
    const int b = blockIdx.x;
    const int boff = b * H + j;

    // ---- weights global -> registers, gate-pair packed ----
    // chainA comp0 = gate i, comp1 = gate f; chainB comp0 = g, comp1 = o.
    v2f wiA[10], wiB[10], whA[10], whB[10], bA, bB;
    {
        const float* WiL = Wih + (size_t)l * 4 * H * H;
        const float* WhL = Whh + (size_t)l * 4 * H * H;
        #pragma unroll
        for (int k = 0; k < 10; ++k) {
            wiA[k][0] = WiL[(0 * H + j) * H + k]; wiA[k][1] = WiL[(1 * H + j) * H + k];
            wiB[k][0] = WiL[(2 * H + j) * H + k]; wiB[k][1] = WiL[(3 * H + j) * H + k];
            whA[k][0] = WhL[(0 * H + j) * H + k]; whA[k][1] = WhL[(1 * H + j) * H + k];
            whB[k][0] = WhL[(2 * H + j) * H + k]; whB[k][1] = WhL[(3 * H + j) * H + k];
        }
        const int bo = l * 4 * H;
        bA[0] = bih[bo + j] + bhh[bo + j];
        bA[1] = bih[bo + H + j] + bhh[bo + H + j];
        bB[0] = bih[bo + 2 * H + j] + bhh[bo + 2 * H + j];
        bB[1] = bih[bo + 3 * H + j] + bhh[bo + 3 * H + j];
    }
    #pragma unroll
    for (int k = 0; k < 10; ++k) { pin2(wiA[k]); pin2(wiB[k]); pin2(whA[k]); pin2(whB[k]); }
    pin2(bA); pin2(bB);

    float h = hp[(l * B + b) * H + j];
    float c = cp[(l * B + b) * H + j];
    // Seed own-h row for first active interval k=l (reads slot(l-1), u=U-1).
    {
        const int ss = (unsigned)(l - 1 + D) & (D - 1);
        v2f hh; hh[0] = h; hh[1] = h;
        *(v2f*)&buf[ss][U - 1][l + 1][2 * j] = hh;
    }

    const bool is_st = (lidx < 10);           // wave0 l=0 primaries stage x
    float xcur[U], xnext[U];
    if (is_st) {
        #pragma unroll
        for (int u = 0; u < U; ++u) {         // window 0 -> slot(-1) = D-1
            float xv = x[(size_t)u * BH + boff];
            v2f xx; xx[0] = xv; xx[1] = xv;
            *(v2f*)&buf[D - 1][u][0][2 * j] = xx;
        }
        #pragma unroll
        for (int u = 0; u < U; ++u) xcur[u] = x[(size_t)(U + u) * BH + boff];
    }
    __syncthreads();

    auto interval = [&](int k) {
        const int slot_w = (unsigned)(k + 2 * D) & (D - 1);
        const int slot_r = (unsigned)(k - 1 + 2 * D) & (D - 1);
        // Prefetch x window k+2 (global latency spans the interval).
        if (is_st && (k + 2) < NWIN) {
            #pragma unroll
            for (int u = 0; u < U; ++u)
                xnext[u] = x[(size_t)((k + 2) * U + u) * BH + boff];
        }
        const unsigned w = (unsigned)(k - l);
        if (w < (unsigned)NWIN) {
            // ---- phase 1: x-projections for all 4 timesteps ----
            v2f aA[U], aB[U];
            #pragma unroll
            for (int u = 0; u < U; ++u) {
                const float* xr = &buf[slot_r][u][l][0];
                v4f q0 = *(const v4f*)(xr + 0);
                v4f q1 = *(const v4f*)(xr + 4);
                v4f q2 = *(const v4f*)(xr + 8);
                v4f q3 = *(const v4f*)(xr + 12);
                v4f q4 = *(const v4f*)(xr + 16);
                v2f a1 = v2fma(wiA[0], lo2(q0), bA);
                v2f a2 = wiA[1] * hi2(q0);
                v2f b1 = v2fma(wiB[0], lo2(q0), bB);
                v2f b2 = wiB[1] * hi2(q0);
                a1 = v2fma(wiA[2], lo2(q1), a1);  a2 = v2fma(wiA[3], hi2(q1), a2);
                b1 = v2fma(wiB[2], lo2(q1), b1);  b2 = v2fma(wiB[3], hi2(q1), b2);
                a1 = v2fma(wiA[4], lo2(q2), a1);  a2 = v2fma(wiA[5], hi2(q2), a2);
                b1 = v2fma(wiB[4], lo2(q2), b1);  b2 = v2fma(wiB[5], hi2(q2), b2);
                a1 = v2fma(wiA[6], lo2(q3), a1);  a2 = v2fma(wiA[7], hi2(q3), a2);
                b1 = v2fma(wiB[6], lo2(q3), b1);  b2 = v2fma(wiB[7], hi2(q3), b2);
                a1 = v2fma(wiA[8], lo2(q4), a1);  a2 = v2fma(wiA[9], hi2(q4), a2);
                b1 = v2fma(wiB[8], lo2(q4), b1);  b2 = v2fma(wiB[9], hi2(q4), b2);
                aA[u] = a1 + a2;
                aB[u] = b1 + b2;
            }
            // ---- phase 2: serial recurrence ----
            float hv[U];
            #pragma unroll
            for (int u = 0; u < U; ++u) {
                const float* hr = (u == 0) ? &buf[slot_r][U - 1][l + 1][0]
                                           : &buf[slot_w][u - 1][l + 1][0];
                v4f q0 = *(const v4f*)(hr + 0);
                v4f q1 = *(const v4f*)(hr + 4);
                v4f q2 = *(const v4f*)(hr + 8);
                v4f q3 = *(const v4f*)(hr + 12);
                v4f q4 = *(const v4f*)(hr + 16);
                v2f a1 = v2fma(whA[0], lo2(q0), aA[u]);
                v2f a2 = whA[1] * hi2(q0);
                v2f b1 = v2fma(whB[0], lo2(q0), aB[u]);
                v2f b2 = whB[1] * hi2(q0);
                a1 = v2fma(whA[2], lo2(q1), a1);  a2 = v2fma(whA[3], hi2(q1), a2);
                b1 = v2fma(whB[2], lo2(q1), b1);  b2 = v2fma(whB[3], hi2(q1), b2);
                a1 = v2fma(whA[4], lo2(q2), a1);  a2 = v2fma(whA[5], hi2(q2), a2);
                b1 = v2fma(whB[4], lo2(q2), b1);  b2 = v2fma(whB[5], hi2(q2), b2);
                a1 = v2fma(whA[6], lo2(q3), a1);  a2 = v2fma(whA[7], hi2(q3), a2);
                b1 = v2fma(whB[6], lo2(q3), b1);  b2 = v2fma(whB[7], hi2(q3), b2);
                a1 = v2fma(whA[8], lo2(q4), a1);  a2 = v2fma(whA[9], hi2(q4), a2);
                b1 = v2fma(whB[8], lo2(q4), b1);  b2 = v2fma(whB[9], hi2(q4), b2);
                const v2f pA = a1 + a2;
                const v2f pB = b1 + b2;
                // activations: same formulas as prior passing kernels
                const float ei = __expf(-pA[0]);
                const float ef = __expf(-pA[1]);
                const float eg = __expf(2.0f * pB[0]);
                const float eo = __expf(-pB[1]);
                const float ig = rcp_f(1.0f + ei);
                const float fg = rcp_f(1.0f + ef);
                const float gr = rcp_f(1.0f + eg);
                const float og = rcp_f(1.0f + eo);
                const float gg = 1.0f - 2.0f * gr;            // tanh(pre_g)
                c = fmaf(fg, c, ig * gg);
                const float th = 1.0f - 2.0f * rcp_f(1.0f + __expf(2.0f * c));
                h = og * th;
                v2f hh; hh[0] = h; hh[1] = h;                 // splat pair
                *(v2f*)&buf[slot_w][u][l + 1][2 * j] = hh;    // l=9 -> pad row 10
                hv[u] = h;
            }
            if (l == L - 1) {                 // batched out-stores (dups benign)
                const int t0 = (int)w * U;
                #pragma unroll
                for (int u = 0; u < U; ++u)
                    out[(size_t)(t0 + u) * BH + boff] = hv[u];
            }
        }
        // Stage x window k+1 into slot(k) (consumed at interval k+1).
        if (is_st && (k + 1) < NWIN) {
            #pragma unroll
            for (int u = 0; u < U; ++u) {
                v2f xx; xx[0] = xcur[u]; xx[1] = xcur[u];
                *(v2f*)&buf[slot_w][u][0][2 * j] = xx;
            }
            #pragma unroll
            for (int u = 0; u < U; ++u) xcur[u] = xnext[u];
        }
    };

    // Epoch loop: barrier once per P intervals. wave1 lags by DELAY intervals,
    // so its cross-wave reads (row 6) always target a strictly earlier epoch.
    for (int rr = 0; rr < NROUNDS; rr += P) {
        #pragma unroll
        for (int pp = 0; pp < P; ++pp) {
            const int k = (rr + pp) - (wv ? DELAY : 0);
            interval(k);
            // Pin LDS program order across intervals (cross-lane deps the
            // compiler cannot see); same-wave DS ops complete in order.
            asm volatile("" ::: "memory");
        }
        __syncthreads();
    }

    hn[(l * B + b) * H + j] = h;   // dup lanes store identical values
    cn[(l * B + b) * H + j] = c;
}

} // namespace

extern "C" void kernel_launch(void* const* d_in, const int* in_sizes, int n_in,
                              void* d_out, int out_size, void* d_ws, size_t ws_size,
                              hipStream_t stream) {
    (void)in_sizes; (void)n_in; (void)d_ws; (void)ws_size; (void)out_size;
    const float* x   = (const float*)d_in[0];
    const float* hp  = (const float*)d_in[1];
    const float* cp  = (const float*)d_in[2];
    const float* Wih = (const float*)d_in[3];
    const float* Whh = (const float*)d_in[4];
    const float* bih = (const float*)d_in[5];
    const float* bhh = (const float*)d_in[6];

    float* out = (float*)d_out;
    float* hn  = out + (size_t)T * B * H;
    float* cn  = hn + (size_t)L * B * H;

    lstm_pipeline<<<dim3(B), dim3(NTHREADS), 0, stream>>>(
        x, hp, cp, Wih, Whh, bih, bhh, out, hn, cn);
}

// Round 5
// 487.992 us; speedup vs baseline: 1.7093x; 1.1015x over previous
//
#include <hip/hip_runtime.h>

namespace {

constexpr int T = 1024;
constexpr int B = 1024;
constexpr int L = 10;
constexpr int H = 10;
constexpr int NTHREADS = 128;      // 2 waves: wave0 = layers 0-5, wave1 = layers 6-9
constexpr int U = 4;               // timesteps per interval
constexpr int NWIN = T / U;        // 256 windows
constexpr int NINT = NWIN + L - 1; // 265 intervals
constexpr int BH = B * H;
constexpr int ROWF = 20;           // splat-pair row: (v0,v0,v1,v1,...,v9,v9)

using v2f = __attribute__((ext_vector_type(2))) float;
using v4f = __attribute__((ext_vector_type(4))) float;

__device__ __forceinline__ v2f v2fma(v2f a, v2f b, v2f c) {
    return __builtin_elementwise_fma(a, b, c);   // v_pk_fma_f32
}
__device__ __forceinline__ void pin2(v2f& v) { asm volatile("" : "+v"(v)); }
__device__ __forceinline__ float rcp_f(float x) { return __builtin_amdgcn_rcpf(x); }
// bare v_exp_f32 (2^x) - weights are pre-scaled by +/-log2e so no mul needed
__device__ __forceinline__ float exp2_f(float x) {
    float r; asm("v_exp_f32 %0, %1" : "=v"(r) : "v"(x)); return r;
}
__device__ __forceinline__ v2f lo2(v4f q) { return __builtin_shufflevector(q, q, 0, 1); }
__device__ __forceinline__ v2f hi2(v4f q) { return __builtin_shufflevector(q, q, 2, 3); }

__global__
__attribute__((amdgpu_flat_work_group_size(NTHREADS, NTHREADS)))
__attribute__((amdgpu_waves_per_eu(2)))   // cap VGPR at 256; 2 waves/SIMD resident
void lstm_pipeline(const float* __restrict__ x,    // [T,B,H]
                   const float* __restrict__ hp,   // [L,B,H]
                   const float* __restrict__ cp,   // [L,B,H]
                   const float* __restrict__ Wih,  // [L,4H,H]
                   const float* __restrict__ Whh,  // [L,4H,H]
                   const float* __restrict__ bih,  // [L,4H]
                   const float* __restrict__ bhh,  // [L,4H]
                   float* __restrict__ out,        // [T,B,H]
                   float* __restrict__ hn,         // [L,B,H]
                   float* __restrict__ cn)         // [L,B,H]
{
    // [parity][u][row][splat row]; row r = input of layer r (r=0: x, r=l+1:
    // layer-l output). Literal parities -> compile-time LDS addresses.
    __shared__ __align__(16) float buf[2][U][L + 1][ROWF];   // 7040 B

    const int tid = threadIdx.x;
    const int wv = tid >> 6;
    const int ln = tid & 63;
    // (l,j) mapping, proven in prior rounds. Dup lanes repeat valid items of
    // the same wave -> identical values/addresses, benign.
    int lidx;
    if (wv == 0) lidx = (ln < 60) ? ln : (ln - 10);              // dup l=5,j=0..3
    else         lidx = (ln < 40) ? (60 + ln) : (90 + (ln - 40) % 10);  // dup l=9
    const int l = lidx / 10;
    const int j = lidx % 10;
    const int b = blockIdx.x;
    const int boff = b * H + j;

    // ---- weights global -> registers, gate-pair packed, exp2-prescaled ----
    // chainA comp0 = gate i, comp1 = gate f; chainB comp0 = g, comp1 = o.
    // Scales: i,f,o -> -log2e (Ei=2^pre'=e^-pre); g -> -2*log2e (Eg=e^-2pre).
    const float NL2E = -1.44269504088896340736f;
    v2f sA; sA[0] = NL2E;        sA[1] = NL2E;
    v2f sB; sB[0] = 2.0f * NL2E; sB[1] = NL2E;
    v2f wiA[10], wiB[10], whA[10], whB[10], bA, bB;
    {
        const float* WiL = Wih + (size_t)l * 4 * H * H;
        const float* WhL = Whh + (size_t)l * 4 * H * H;
        #pragma unroll
        for (int k = 0; k < 10; ++k) {
            v2f t;
            t[0] = WiL[(0 * H + j) * H + k]; t[1] = WiL[(1 * H + j) * H + k];
            wiA[k] = t * sA;
            t[0] = WiL[(2 * H + j) * H + k]; t[1] = WiL[(3 * H + j) * H + k];
            wiB[k] = t * sB;
            t[0] = WhL[(0 * H + j) * H + k]; t[1] = WhL[(1 * H + j) * H + k];
            whA[k] = t * sA;
            t[0] = WhL[(2 * H + j) * H + k]; t[1] = WhL[(3 * H + j) * H + k];
            whB[k] = t * sB;
        }
        const int bo = l * 4 * H;
        bA[0] = bih[bo + j] + bhh[bo + j];
        bA[1] = bih[bo + H + j] + bhh[bo + H + j];
        bB[0] = bih[bo + 2 * H + j] + bhh[bo + 2 * H + j];
        bB[1] = bih[bo + 3 * H + j] + bhh[bo + 3 * H + j];
        bA = bA * sA;
        bB = bB * sB;
    }
    #pragma unroll
    for (int k = 0; k < 10; ++k) { pin2(wiA[k]); pin2(wiB[k]); pin2(whA[k]); pin2(whB[k]); }
    pin2(bA); pin2(bB);

    float h = hp[(l * B + b) * H + j];
    float c = cp[(l * B + b) * H + j];
    // Seed own-h row for first active interval k=l (reads parity rp(l)=(l+1)&1,
    // u=U-1). Layer l's own writes to that row start at parity l&1 -> safe.
    {
        v2f hh; hh[0] = h; hh[1] = h;
        *(v2f*)&buf[(l + 1) & 1][U - 1][l + 1][2 * j] = hh;
    }

    const bool is_st = (lidx < 10);           // wave0 l=0 primaries stage x
    float xcur[U], xnext[U];
    if (is_st) {
        #pragma unroll
        for (int u = 0; u < U; ++u) {         // window 0 -> parity 1 (rp of k=0)
            float xv = x[(size_t)u * BH + boff];
            v2f xx; xx[0] = xv; xx[1] = xv;
            *(v2f*)&buf[1][u][0][2 * j] = xx;
        }
        #pragma unroll
        for (int u = 0; u < U; ++u) xcur[u] = x[(size_t)(U + u) * BH + boff];
    }
    __syncthreads();

    auto interval = [&](int k, int wp, int rp) {
        // Prefetch x window k+2 (global latency spans the interval).
        if (is_st && (k + 2) < NWIN) {
            #pragma unroll
            for (int u = 0; u < U; ++u)
                xnext[u] = x[(size_t)((k + 2) * U + u) * BH + boff];
        }
        const unsigned w = (unsigned)(k - l);
        if (w < (unsigned)NWIN) {
            // Barrier-stable u=0 h-row: preload before phase 1 for latency cover.
            v4f hq0 = *(const v4f*)&buf[rp][U - 1][l + 1][0];
            v4f hq1 = *(const v4f*)&buf[rp][U - 1][l + 1][4];
            v4f hq2 = *(const v4f*)&buf[rp][U - 1][l + 1][8];
            v4f hq3 = *(const v4f*)&buf[rp][U - 1][l + 1][12];
            v4f hq4 = *(const v4f*)&buf[rp][U - 1][l + 1][16];
            // ---- phase 1: x-projections for all 4 timesteps ----
            v2f aA[U], aB[U];
            #pragma unroll
            for (int u = 0; u < U; ++u) {
                const float* xr = &buf[rp][u][l][0];
                v4f q0 = *(const v4f*)(xr + 0);
                v4f q1 = *(const v4f*)(xr + 4);
                v4f q2 = *(const v4f*)(xr + 8);
                v4f q3 = *(const v4f*)(xr + 12);
                v4f q4 = *(const v4f*)(xr + 16);
                v2f a1 = v2fma(wiA[0], lo2(q0), bA);
                v2f a2 = wiA[1] * hi2(q0);
                v2f b1 = v2fma(wiB[0], lo2(q0), bB);
                v2f b2 = wiB[1] * hi2(q0);
                a1 = v2fma(wiA[2], lo2(q1), a1);  a2 = v2fma(wiA[3], hi2(q1), a2);
                b1 = v2fma(wiB[2], lo2(q1), b1);  b2 = v2fma(wiB[3], hi2(q1), b2);
                a1 = v2fma(wiA[4], lo2(q2), a1);  a2 = v2fma(wiA[5], hi2(q2), a2);
                b1 = v2fma(wiB[4], lo2(q2), b1);  b2 = v2fma(wiB[5], hi2(q2), b2);
                a1 = v2fma(wiA[6], lo2(q3), a1);  a2 = v2fma(wiA[7], hi2(q3), a2);
                b1 = v2fma(wiB[6], lo2(q3), b1);  b2 = v2fma(wiB[7], hi2(q3), b2);
                a1 = v2fma(wiA[8], lo2(q4), a1);  a2 = v2fma(wiA[9], hi2(q4), a2);
                b1 = v2fma(wiB[8], lo2(q4), b1);  b2 = v2fma(wiB[9], hi2(q4), b2);
                aA[u] = a1 + a2;
                aB[u] = b1 + b2;
            }
            // ---- phase 2: serial recurrence ----
            float hv[U];
            #pragma unroll
            for (int u = 0; u < U; ++u) {
                v4f q0, q1, q2, q3, q4;
                if (u == 0) { q0 = hq0; q1 = hq1; q2 = hq2; q3 = hq3; q4 = hq4; }
                else {
                    const float* hr = &buf[wp][u - 1][l + 1][0];
                    q0 = *(const v4f*)(hr + 0);
                    q1 = *(const v4f*)(hr + 4);
                    q2 = *(const v4f*)(hr + 8);
                    q3 = *(const v4f*)(hr + 12);
                    q4 = *(const v4f*)(hr + 16);
                }
                v2f a1 = v2fma(whA[0], lo2(q0), aA[u]);
                v2f a2 = whA[1] * hi2(q0);
                v2f b1 = v2fma(whB[0], lo2(q0), aB[u]);
                v2f b2 = whB[1] * hi2(q0);
                a1 = v2fma(whA[2], lo2(q1), a1);  a2 = v2fma(whA[3], hi2(q1), a2);
                b1 = v2fma(whB[2], lo2(q1), b1);  b2 = v2fma(whB[3], hi2(q1), b2);
                a1 = v2fma(whA[4], lo2(q2), a1);  a2 = v2fma(whA[5], hi2(q2), a2);
                b1 = v2fma(whB[4], lo2(q2), b1);  b2 = v2fma(whB[5], hi2(q2), b2);
                a1 = v2fma(whA[6], lo2(q3), a1);  a2 = v2fma(whA[7], hi2(q3), a2);
                b1 = v2fma(whB[6], lo2(q3), b1);  b2 = v2fma(whB[7], hi2(q3), b2);
                a1 = v2fma(whA[8], lo2(q4), a1);  a2 = v2fma(whA[9], hi2(q4), a2);
                b1 = v2fma(whB[8], lo2(q4), b1);  b2 = v2fma(whB[9], hi2(q4), b2);
                const v2f pA = a1 + a2;   // (pre_i, pre_f) * -log2e
                const v2f pB = b1 + b2;   // (pre_g * -2log2e, pre_o * -log2e)
                // 7-trans activation block (5 exp2 + 2 rcp):
                //   Ei=e^-pi Ef=e^-pf Eg=e^-2pg Eo=e^-po
                //   c' = fg*c + ig*tanh(pg) = [c*d2 + (1-Eg)*d1] / (d1*d2)
                //        d1 = 1+Ef, d2 = (1+Ei)(1+Eg)
                //   h  = og*tanh(c') = (1-Ec) / ((1+Eo)(1+Ec)), Ec = e^-2c'
                const float Ei = exp2_f(pA[0]);
                const float Ef = exp2_f(pA[1]);
                const float Eg = exp2_f(pB[0]);
                const float Eo = exp2_f(pB[1]);
                const float d1 = 1.0f + Ef;
                const float e1 = 1.0f + Ei;
                const float e2 = 1.0f + Eg;
                const float d2 = e1 * e2;
                const float num = fmaf(c, d2, (1.0f - Eg) * d1);
                c = num * rcp_f(d1 * d2);
                const float Ec = exp2_f((2.0f * NL2E) * c);
                const float o1 = 1.0f + Eo;
                const float o2 = 1.0f + Ec;
                h = (1.0f - Ec) * rcp_f(o1 * o2);
                v2f hh; hh[0] = h; hh[1] = h;                 // splat pair
                *(v2f*)&buf[wp][u][l + 1][2 * j] = hh;        // l=9 -> pad row 10
                hv[u] = h;
            }
            if (l == L - 1) {                 // batched out-stores (dups benign)
                const int t0 = (int)w * U;
                #pragma unroll
                for (int u = 0; u < U; ++u)
                    out[(size_t)(t0 + u) * BH + boff] = hv[u];
            }
        }
        // Stage x window k+1 into parity wp (consumed at interval k+1).
        if (is_st && (k + 1) < NWIN) {
            #pragma unroll
            for (int u = 0; u < U; ++u) {
                v2f xx; xx[0] = xcur[u]; xx[1] = xcur[u];
                *(v2f*)&buf[wp][u][0][2 * j] = xx;
            }
            #pragma unroll
            for (int u = 0; u < U; ++u) xcur[u] = xnext[u];
        }
        __syncthreads();
    };

    for (int kk = 0; kk < NINT + 1; kk += 2) {   // literal parities
        interval(kk, 0, 1);
        interval(kk + 1, 1, 0);
    }

    hn[(l * B + b) * H + j] = h;   // dup lanes store identical values
    cn[(l * B + b) * H + j] = c;
}

} // namespace

extern "C" void kernel_launch(void* const* d_in, const int* in_sizes, int n_in,
                              void* d_out, int out_size, void* d_ws, size_t ws_size,
                              hipStream_t stream) {
    (void)in_sizes; (void)n_in; (void)d_ws; (void)ws_size; (void)out_size;
    const float* x   = (const float*)d_in[0];
    const float* hp  = (const float*)d_in[1];
    const float* cp  = (const float*)d_in[2];
    const float* Wih = (const float*)d_in[3];
    const float* Whh = (const float*)d_in[4];
    const float* bih = (const float*)d_in[5];
    const float* bhh = (const float*)d_in[6];

    float* out = (float*)d_out;
    float* hn  = out + (size_t)T * B * H;
    float* cn  = hn + (size_t)L * B * H;

    lstm_pipeline<<<dim3(B), dim3(NTHREADS), 0, stream>>>(
        x, hp, cp, Wih, Whh, bih, bhh, out, hn, cn);
}

// Round 6
// 484.521 us; speedup vs baseline: 1.7215x; 1.0072x over previous
//
#include <hip/hip_runtime.h>

namespace {

constexpr int T = 1024;
constexpr int B = 1024;
constexpr int L = 10;
constexpr int H = 10;
constexpr int NTHREADS = 128;      // 2 waves: wave0 = layers 0-5, wave1 = layers 6-9
constexpr int U = 4;               // timesteps per interval
constexpr int NWIN = T / U;        // 256 windows
constexpr int NINT = NWIN + L - 1; // 265 intervals
constexpr int BH = B * H;
constexpr int ROWF = 20;           // splat-pair row: (v0,v0,v1,v1,...,v9,v9)

using v2f = __attribute__((ext_vector_type(2))) float;
using v4f = __attribute__((ext_vector_type(4))) float;

__device__ __forceinline__ v2f v2fma(v2f a, v2f b, v2f c) {
    return __builtin_elementwise_fma(a, b, c);   // v_pk_fma_f32
}
__device__ __forceinline__ void pin2(v2f& v) { asm volatile("" : "+v"(v)); }
__device__ __forceinline__ float rcp_f(float x) { return __builtin_amdgcn_rcpf(x); }
// bare v_exp_f32 (2^x) - weights are pre-scaled by +/-log2e so no mul needed
__device__ __forceinline__ float exp2_f(float x) {
    float r; asm("v_exp_f32 %0, %1" : "=v"(r) : "v"(x)); return r;
}
__device__ __forceinline__ v2f lo2(v4f q) { return __builtin_shufflevector(q, q, 0, 1); }
__device__ __forceinline__ v2f hi2(v4f q) { return __builtin_shufflevector(q, q, 2, 3); }
#define LDS_FENCE asm volatile("" ::: "memory")

__global__
__attribute__((amdgpu_flat_work_group_size(NTHREADS, NTHREADS)))
__attribute__((amdgpu_waves_per_eu(2)))   // cap VGPR at 256; 2 waves/SIMD resident
void lstm_pipeline(const float* __restrict__ x,    // [T,B,H]
                   const float* __restrict__ hp,   // [L,B,H]
                   const float* __restrict__ cp,   // [L,B,H]
                   const float* __restrict__ Wih,  // [L,4H,H]
                   const float* __restrict__ Whh,  // [L,4H,H]
                   const float* __restrict__ bih,  // [L,4H]
                   const float* __restrict__ bhh,  // [L,4H]
                   float* __restrict__ out,        // [T,B,H]
                   float* __restrict__ hn,         // [L,B,H]
                   float* __restrict__ cn)         // [L,B,H]
{
    // [parity][u][row][splat row]; row r = input of layer r (r=0: x, r=l+1:
    // layer-l output). Literal parities -> compile-time LDS addresses.
    __shared__ __align__(16) float buf[2][U][L + 1][ROWF];   // 7040 B

    const int tid = threadIdx.x;
    const int wv = tid >> 6;
    const int ln = tid & 63;
    // (l,j) mapping, proven in prior rounds. Dup lanes repeat valid items of
    // the same wave -> identical values/addresses, benign.
    int lidx;
    if (wv == 0) lidx = (ln < 60) ? ln : (ln - 10);              // dup l=5,j=0..3
    else         lidx = (ln < 40) ? (60 + ln) : (90 + (ln - 40) % 10);  // dup l=9
    const int l = lidx / 10;
    const int j = lidx % 10;
    const int b = blockIdx.x;
    const int boff = b * H + j;

    // ---- weights global -> registers, gate-pair packed, exp2-prescaled ----
    // chainA comp0 = gate i, comp1 = gate f; chainB comp0 = g, comp1 = o.
    // Scales: i,f,o -> -log2e (Ei=2^pre'=e^-pre); g -> -2*log2e (Eg=e^-2pre).
    const float NL2E = -1.44269504088896340736f;
    v2f sA; sA[0] = NL2E;        sA[1] = NL2E;
    v2f sB; sB[0] = 2.0f * NL2E; sB[1] = NL2E;
    v2f wiA[10], wiB[10], whA[10], whB[10], bA, bB;
    {
        const float* WiL = Wih + (size_t)l * 4 * H * H;
        const float* WhL = Whh + (size_t)l * 4 * H * H;
        #pragma unroll
        for (int k = 0; k < 10; ++k) {
            v2f t;
            t[0] = WiL[(0 * H + j) * H + k]; t[1] = WiL[(1 * H + j) * H + k];
            wiA[k] = t * sA;
            t[0] = WiL[(2 * H + j) * H + k]; t[1] = WiL[(3 * H + j) * H + k];
            wiB[k] = t * sB;
            t[0] = WhL[(0 * H + j) * H + k]; t[1] = WhL[(1 * H + j) * H + k];
            whA[k] = t * sA;
            t[0] = WhL[(2 * H + j) * H + k]; t[1] = WhL[(3 * H + j) * H + k];
            whB[k] = t * sB;
        }
        const int bo = l * 4 * H;
        bA[0] = bih[bo + j] + bhh[bo + j];
        bA[1] = bih[bo + H + j] + bhh[bo + H + j];
        bB[0] = bih[bo + 2 * H + j] + bhh[bo + 2 * H + j];
        bB[1] = bih[bo + 3 * H + j] + bhh[bo + 3 * H + j];
        bA = bA * sA;
        bB = bB * sB;
    }
    #pragma unroll
    for (int k = 0; k < 10; ++k) { pin2(wiA[k]); pin2(wiB[k]); pin2(whA[k]); pin2(whB[k]); }
    pin2(bA); pin2(bB);

    float h = hp[(l * B + b) * H + j];
    float c = cp[(l * B + b) * H + j];
    // Seed own-h row for first active interval k=l (P2(l) u=0 reads parity
    // (l-1)&1 == (l+1)&1, row l+1, u=U-1).
    {
        v2f hh; hh[0] = h; hh[1] = h;
        *(v2f*)&buf[(l + 1) & 1][U - 1][l + 1][2 * j] = hh;
    }

    const bool is_st = (lidx < 10);           // wave0 l=0 primaries stage x
    float xcur[U], xnext[U];
    if (is_st) {
        #pragma unroll
        for (int u = 0; u < U; ++u) {         // window 0 -> parity 1 (rp of k=0)
            float xv = x[(size_t)u * BH + boff];
            v2f xx; xx[0] = xv; xx[1] = xv;
            *(v2f*)&buf[1][u][0][2 * j] = xx;
        }
        #pragma unroll
        for (int u = 0; u < U; ++u) xcur[u] = x[(size_t)(U + u) * BH + boff];
    }
    __syncthreads();

    // x-projection accumulators; for wave1 they live across a barrier.
    v2f aA[U], aB[U];

    auto prefetchx = [&](int k) {
        if (is_st && (k + 2) < NWIN) {
            #pragma unroll
            for (int u = 0; u < U; ++u)
                xnext[u] = x[(size_t)((k + 2) * U + u) * BH + boff];
        }
    };

    // phase1(k): x-projections for window k-l, reading slot k-1 (parity rp).
    auto phase1 = [&](int k, int rp) {
        const unsigned w = (unsigned)(k - l);
        if (w < (unsigned)NWIN) {
            #pragma unroll
            for (int u = 0; u < U; ++u) {
                const float* xr = &buf[rp][u][l][0];
                v4f q0 = *(const v4f*)(xr + 0);
                v4f q1 = *(const v4f*)(xr + 4);
                v4f q2 = *(const v4f*)(xr + 8);
                v4f q3 = *(const v4f*)(xr + 12);
                v4f q4 = *(const v4f*)(xr + 16);
                // single 10-deep chains; 8 independent chains across (u, A/B)
                v2f a  = v2fma(wiA[0], lo2(q0), bA);
                v2f bv = v2fma(wiB[0], lo2(q0), bB);
                a = v2fma(wiA[1], hi2(q0), a);  bv = v2fma(wiB[1], hi2(q0), bv);
                a = v2fma(wiA[2], lo2(q1), a);  bv = v2fma(wiB[2], lo2(q1), bv);
                a = v2fma(wiA[3], hi2(q1), a);  bv = v2fma(wiB[3], hi2(q1), bv);
                a = v2fma(wiA[4], lo2(q2), a);  bv = v2fma(wiB[4], lo2(q2), bv);
                a = v2fma(wiA[5], hi2(q2), a);  bv = v2fma(wiB[5], hi2(q2), bv);
                a = v2fma(wiA[6], lo2(q3), a);  bv = v2fma(wiB[6], lo2(q3), bv);
                a = v2fma(wiA[7], hi2(q3), a);  bv = v2fma(wiB[7], hi2(q3), bv);
                a = v2fma(wiA[8], lo2(q4), a);  bv = v2fma(wiB[8], lo2(q4), bv);
                a = v2fma(wiA[9], hi2(q4), a);  bv = v2fma(wiB[9], hi2(q4), bv);
                aA[u] = a;
                aB[u] = bv;
            }
        }
    };

    // phase2(k): recurrence for window k-l; writes slot k (parity wp),
    // u=0 h-row from slot k-1 (parity rp). Consumes aA/aB from phase1(k).
    auto phase2 = [&](int k, int wp, int rp) {
        const unsigned w = (unsigned)(k - l);
        if (w < (unsigned)NWIN) {
            // Barrier-stable u=0 h-row: preload for latency cover.
            v4f hq0 = *(const v4f*)&buf[rp][U - 1][l + 1][0];
            v4f hq1 = *(const v4f*)&buf[rp][U - 1][l + 1][4];
            v4f hq2 = *(const v4f*)&buf[rp][U - 1][l + 1][8];
            v4f hq3 = *(const v4f*)&buf[rp][U - 1][l + 1][12];
            v4f hq4 = *(const v4f*)&buf[rp][U - 1][l + 1][16];
            float hv[U];
            #pragma unroll
            for (int u = 0; u < U; ++u) {
                v4f q0, q1, q2, q3, q4;
                if (u == 0) { q0 = hq0; q1 = hq1; q2 = hq2; q3 = hq3; q4 = hq4; }
                else {
                    const float* hr = &buf[wp][u - 1][l + 1][0];
                    q0 = *(const v4f*)(hr + 0);
                    q1 = *(const v4f*)(hr + 4);
                    q2 = *(const v4f*)(hr + 8);
                    q3 = *(const v4f*)(hr + 12);
                    q4 = *(const v4f*)(hr + 16);
                }
                // split chains: shorter dep path on the critical recurrence
                v2f a1 = v2fma(whA[0], lo2(q0), aA[u]);
                v2f a2 = whA[1] * hi2(q0);
                v2f b1 = v2fma(whB[0], lo2(q0), aB[u]);
                v2f b2 = whB[1] * hi2(q0);
                a1 = v2fma(whA[2], lo2(q1), a1);  a2 = v2fma(whA[3], hi2(q1), a2);
                b1 = v2fma(whB[2], lo2(q1), b1);  b2 = v2fma(whB[3], hi2(q1), b2);
                a1 = v2fma(whA[4], lo2(q2), a1);  a2 = v2fma(whA[5], hi2(q2), a2);
                b1 = v2fma(whB[4], lo2(q2), b1);  b2 = v2fma(whB[5], hi2(q2), b2);
                a1 = v2fma(whA[6], lo2(q3), a1);  a2 = v2fma(whA[7], hi2(q3), a2);
                b1 = v2fma(whB[6], lo2(q3), b1);  b2 = v2fma(whB[7], hi2(q3), b2);
                a1 = v2fma(whA[8], lo2(q4), a1);  a2 = v2fma(whA[9], hi2(q4), a2);
                b1 = v2fma(whB[8], lo2(q4), b1);  b2 = v2fma(whB[9], hi2(q4), b2);
                const v2f pA = a1 + a2;   // (pre_i, pre_f) * -log2e
                const v2f pB = b1 + b2;   // (pre_g * -2log2e, pre_o * -log2e)
                // 7-trans activation block (5 exp2 + 2 rcp):
                //   c' = [c*d2 + (1-Eg)*d1] / (d1*d2), d1=1+Ef, d2=(1+Ei)(1+Eg)
                //   h  = (1-Ec) / ((1+Eo)(1+Ec)), Ec = e^-2c'
                const float Ei = exp2_f(pA[0]);
                const float Ef = exp2_f(pA[1]);
                const float Eg = exp2_f(pB[0]);
                const float Eo = exp2_f(pB[1]);
                const float d1 = 1.0f + Ef;
                const float e1 = 1.0f + Ei;
                const float e2 = 1.0f + Eg;
                const float d2 = e1 * e2;
                const float num = fmaf(c, d2, (1.0f - Eg) * d1);
                c = num * rcp_f(d1 * d2);
                const float Ec = exp2_f((2.0f * NL2E) * c);
                const float o1 = 1.0f + Eo;
                const float o2 = 1.0f + Ec;
                h = (1.0f - Ec) * rcp_f(o1 * o2);
                v2f hh; hh[0] = h; hh[1] = h;                 // splat pair
                *(v2f*)&buf[wp][u][l + 1][2 * j] = hh;        // l=9 -> pad row 10
                hv[u] = h;
            }
            if (l == L - 1) {                 // batched out-stores (dups benign)
                const int t0 = (int)w * U;
                #pragma unroll
                for (int u = 0; u < U; ++u)
                    out[(size_t)(t0 + u) * BH + boff] = hv[u];
            }
        }
    };

    auto stagex = [&](int k, int wp) {
        if (is_st && (k + 1) < NWIN) {
            #pragma unroll
            for (int u = 0; u < U; ++u) {
                v2f xx; xx[0] = xcur[u]; xx[1] = xcur[u];
                *(v2f*)&buf[wp][u][0][2 * j] = xx;
            }
            #pragma unroll
            for (int u = 0; u < U; ++u) xcur[u] = xnext[u];
        }
    };

    // Anti-aligned schedule: wave0 runs [P1(k); P2(k)], wave1 runs
    // [P2(k-1); P1(k)] -- so one wave's dense dot-product phase overlaps the
    // other wave's latency-bound recurrence phase, every interval.
    // Cross-wave dep (row 6): wave1 P1(k) reads what wave0 P2(k-1) wrote
    // before the previous barrier. Same-wave deps are in-order LDS.
    if (wv == 0) {
        for (int kk = 0; kk < NINT + 1; kk += 2) {   // literal parities
            prefetchx(kk);
            phase1(kk, 1);        LDS_FENCE;
            phase2(kk, 0, 1);     LDS_FENCE;
            stagex(kk, 0);
            __syncthreads();
            prefetchx(kk + 1);
            phase1(kk + 1, 0);    LDS_FENCE;
            phase2(kk + 1, 1, 0); LDS_FENCE;
            stagex(kk + 1, 1);
            __syncthreads();
        }
    } else {
        for (int kk = 0; kk < NINT + 1; kk += 2) {
            phase2(kk - 1, 1, 0); LDS_FENCE;   // slot kk-1 parity 1, u0 from parity 0
            phase1(kk, 1);
            __syncthreads();
            phase2(kk, 0, 1);     LDS_FENCE;
            phase1(kk + 1, 0);
            __syncthreads();
        }
    }

    hn[(l * B + b) * H + j] = h;   // dup lanes store identical values
    cn[(l * B + b) * H + j] = c;
}

} // namespace

extern "C" void kernel_launch(void* const* d_in, const int* in_sizes, int n_in,
                              void* d_out, int out_size, void* d_ws, size_t ws_size,
                              hipStream_t stream) {
    (void)in_sizes; (void)n_in; (void)d_ws; (void)ws_size; (void)out_size;
    const float* x   = (const float*)d_in[0];
    const float* hp  = (const float*)d_in[1];
    const float* cp  = (const float*)d_in[2];
    const float* Wih = (const float*)d_in[3];
    const float* Whh = (const float*)d_in[4];
    const float* bih = (const float*)d_in[5];
    const float* bhh = (const float*)d_in[6];

    float* out = (float*)d_out;
    float* hn  = out + (size_t)T * B * H;
    float* cn  = hn + (size_t)L * B * H;

    lstm_pipeline<<<dim3(B), dim3(NTHREADS), 0, stream>>>(
        x, hp, cp, Wih, Whh, bih, bhh, out, hn, cn);
}